// Round 6
// baseline (162.074 us; speedup 1.0000x reference)
//
#include <hip/hip_runtime.h>

// Bilinear backward warp: img [B,C,H,W] f32, flo [B,2,H,W] f32 -> out [B,C,H,W] f32
// B=8, C=64, H=256, W=448
//
// R6: wave-private staging, ZERO barriers. Each wave owns a 4x64 output tile;
// stages a 12x72 halo band of the current channel into its private LDS slice
// via 4x global_load_lds(width=16) (per-lane global src, wave-uniform LDS
// dest), double-buffered with depth-2 issue. Waits are per-wave counted
// s_waitcnt vmcnt(N) only. 27.9KB LDS/block -> 5 blocks/CU = 20 waves/CU,
// all independent -> latency hidden by TLP instead of defeated by barriers.

#define BN 8
#define CN 64
#define HN 256
#define WN 448
#define HW (HN * WN)
#define R 4               // output rows per wave
#define HALO 4
#define BAND 12           // staged rows: lo = h0-4 .. h0+7
#define WCOLS 64          // output cols per wave
#define LCOLS 72          // staged cols = WCOLS + 2*HALO
#define BWORDS (BAND * LCOLS)   // 864 words = 3456 B
#define TPB 256           // 4 waves
#define NXCD 8

typedef __attribute__((address_space(1))) const void glb_v;
typedef __attribute__((address_space(3))) void lds_v;

__global__ __launch_bounds__(TPB, 5) void warp_kernel(const float* __restrict__ img,
                                                      const float* __restrict__ flo,
                                                      float* __restrict__ out) {
    // per-wave private double buffer; +8 words pad (x0+1 read at col 71 stays in-band anyway)
    __shared__ float lds[4][2][BWORDS + 8];

    // XCD swizzle: 896 blocks = 112/XCD; XCD k owns batch k entirely.
    const int nwg = gridDim.x;            // 896
    const int cpx = nwg / NXCD;           // 112
    const int bid = blockIdx.x;
    const int wgid = (bid % NXCD) * cpx + (bid / NXCD);

    const int b  = wgid / cpx;            // 0..7
    const int t  = wgid % cpx;            // 0..111: 16 row-bands x 7 col-tiles
    const int ct = t % 7;                 // column tile
    const int hb = (t / 7) * 16;          // 16 rows per block (4 waves x 4 rows)

    const int wid  = threadIdx.x >> 6;    // 0..3
    const int lane = threadIdx.x & 63;

    const int h0 = hb + wid * R;
    const int c0 = ct * WCOLS;
    const int w  = c0 + lane;

    int lo = h0 - HALO;
    lo = lo < 0 ? 0 : (lo > HN - BAND ? HN - BAND : lo);
    int bc = c0 - HALO;
    bc = bc < 0 ? 0 : (bc > WN - LCOLS ? WN - LCOLS : bc);

    const float* imgb = img + (size_t)b * CN * HW;
    const float* flob = flo + (size_t)b * 2 * HW;

    // ---- per-pixel setup (channel-invariant) ----
    float wa[R], wb[R], wc[R], wd[R];
    int sA[R], sB[R];     // LDS word offsets (clamped; garbage replaced on fb)
    int gA[R], gB[R];     // plane-relative global offsets for fallback
    int dxv[R];
    bool fb[R];
#pragma unroll
    for (int r = 0; r < R; ++r) {
        const int h = h0 + r;
        const int hw = h * WN + w;
        const float fx = flob[hw];
        const float fy = flob[HW + hw];
        const float x = (float)w + fx;
        const float y = (float)h + fy;
        int x0 = (int)x;                 // trunc toward zero (matches ref)
        int x1 = x0 + 1;
        int y0 = (int)y;
        int y1 = y0 + 1;
        x0 = min(max(x0, 0), WN - 1);
        x1 = min(max(x1, 0), WN - 1);
        y0 = min(max(y0, 0), HN - 1);
        y1 = min(max(y1, 0), HN - 1);
        const float x0f = (float)x0, x1f = (float)x1;
        const float y0f = (float)y0, y1f = (float)y1;
        wa[r] = (x1f - x) * (y1f - y);
        wb[r] = (x1f - x) * (y - y0f);
        wc[r] = (x - x0f) * (y1f - y);
        wd[r] = (x - x0f) * (y - y0f);
        const int dx = x1 - x0;          // 0 only at image edge clip
        dxv[r] = dx;
        const int cA = x0 - bc;          // desired LDS col
        const bool okx = (cA >= 0) && (cA + dx <= LCOLS - 1);
        const bool oky = (y0 >= lo) && (y1 <= lo + BAND - 1);
        fb[r] = !(okx && oky);
        const int cc = min(max(cA, 0), LCOLS - 2);
        const int rA = min(max(y0 - lo, 0), BAND - 1);
        const int rB = min(max(y1 - lo, 0), BAND - 1);
        sA[r] = rA * LCOLS + cc;
        sB[r] = rB * LCOLS + cc;
        gA[r] = y0 * WN + x0;
        gB[r] = y1 * WN + x0;
    }

    // ---- staging source offsets: band = 216 chunks of 16B; 4 instrs/channel ----
    // chunk = k*64 + lane; row = chunk/18, colw = (chunk%18)*4
    int srcW[4];
#pragma unroll
    for (int k = 0; k < 4; ++k) {
        const int chunk = k * 64 + lane;
        const int row = chunk / 18;
        const int colw = (chunk - row * 18) * 4;
        srcW[k] = row * WN + colw;       // band-relative global word offset
    }
    float* buf0 = &lds[wid][0][0];
    float* buf1 = &lds[wid][1][0];

    auto stage = [&](int bufi, int c) {
        const float* s = imgb + (size_t)c * HW + (size_t)lo * WN + bc;
        char* d = (char*)(bufi ? buf1 : buf0);    // wave-uniform dest base
        __builtin_amdgcn_global_load_lds((glb_v*)(s + srcW[0]), (lds_v*)(d),        16, 0, 0);
        __builtin_amdgcn_global_load_lds((glb_v*)(s + srcW[1]), (lds_v*)(d + 1024), 16, 0, 0);
        __builtin_amdgcn_global_load_lds((glb_v*)(s + srcW[2]), (lds_v*)(d + 2048), 16, 0, 0);
        if (lane < 24)
            __builtin_amdgcn_global_load_lds((glb_v*)(s + srcW[3]), (lds_v*)(d + 3072), 16, 0, 0);
    };

    stage(0, 0);
    stage(1, 1);

    float* outp = out + (size_t)b * CN * HW + (size_t)h0 * WN + c0 + lane;

    for (int c = 0; c < CN; ++c) {
        // Per-wave FIFO: [stage(c) 4][stores(c-1) 4][stage(c+1) 4] in steady state.
        // Wait so that stage(c) is retired; younger ops stay in flight.
        if (c == 0 || c == CN - 1) {
            asm volatile("s_waitcnt vmcnt(4)" ::: "memory");
        } else {
            asm volatile("s_waitcnt vmcnt(8)" ::: "memory");
        }

        const float* buf = (c & 1) ? buf1 : buf0;
        const float* pg = imgb + (size_t)c * HW;
#pragma unroll
        for (int r = 0; r < R; ++r) {
            float a0 = buf[sA[r]];
            float a1 = buf[sA[r] + 1];   // ds_read2_b32 with a0
            float b0 = buf[sB[r]];
            float b1 = buf[sB[r] + 1];
            if (fb[r]) {                 // rare: exec-masked fixup
                a0 = pg[gA[r]];
                a1 = pg[gA[r] + dxv[r]];
                b0 = pg[gB[r]];
                b1 = pg[gB[r] + dxv[r]];
            }
            const float Ic = dxv[r] ? a1 : a0;
            const float Id = dxv[r] ? b1 : b0;
            outp[(size_t)c * HW + r * WN] = wa[r] * a0 + wb[r] * b0 + wc[r] * Ic + wd[r] * Id;
        }

        // depth-2 prefetch: buf[c&1] was just consumed; safe to re-target.
        if (c + 2 < CN) stage(c & 1, c + 2);
    }
}

extern "C" void kernel_launch(void* const* d_in, const int* in_sizes, int n_in,
                              void* d_out, int out_size, void* d_ws, size_t ws_size,
                              hipStream_t stream) {
    const float* img = (const float*)d_in[0];
    const float* flo = (const float*)d_in[1];
    float* out = (float*)d_out;

    const int grid = BN * (HN / 16) * (WN / WCOLS);   // 8*16*7 = 896 blocks
    warp_kernel<<<grid, TPB, 0, stream>>>(img, flo, out);
}

// Round 7
// 109.664 us; speedup vs baseline: 1.4779x; 1.4779x over previous
//
#include <hip/hip_runtime.h>

// Bilinear backward warp: img [B,C,H,W] f32, flo [B,2,H,W] f32 -> out [B,C,H,W] f32
// B=8, C=64, H=256, W=448
//
// R7 = R3's verified-exact skeleton (block-wide staging + __syncthreads drain,
// which beat all counted-vmcnt variants) with the round count halved:
// 4 rotating LDS buffers, stage channels {c+2,c+3} while computing {c,c+1},
// one barrier per 2 channels (16 rounds/block instead of 64), channel-split
// across 2 blocks (grid 1024) so 2 blocks/CU stay resident and overlap drains.

#define BN 8
#define CN 64
#define HN 256
#define WN 448
#define HW (HN * WN)
#define R 4              // output rows per block
#define BAND 10          // staged img rows per channel (lo = h0-3)
#define TPB WN           // 448 threads = 7 waves
#define NXCD 8
#define CSPLIT 2
#define CLOOP (CN / CSPLIT)   // 32 channels per block
#define ROUNDS (CLOOP / 2)    // 16 rounds of 2 channels

typedef __attribute__((address_space(1))) const void glb_v;
typedef __attribute__((address_space(3))) void lds_v;

__global__ __launch_bounds__(TPB) void warp_kernel(const float* __restrict__ img,
                                                   const float* __restrict__ flo,
                                                   float* __restrict__ out) {
    // 4 buffers x (4480+4) floats = 71744 B -> 2 blocks/CU
    __shared__ float lds[4][BAND * WN + 4];

    // XCD swizzle: 1024 blocks = 128/XCD = one batch per XCD; adjacent wgids
    // are the two channel-halves of the same tile -> share L2 row bands.
    const int nwg = gridDim.x;            // 1024
    const int cpx = nwg / NXCD;           // 128
    const int bid = blockIdx.x;
    const int wgid = (bid % NXCD) * cpx + (bid / NXCD);

    const int b    = wgid / cpx;          // 0..7
    const int rem  = wgid % cpx;          // 0..127
    const int tile = rem >> 1;            // 0..63
    const int ch0  = (rem & 1) * CLOOP;   // 0 or 32
    const int h0   = tile * R;
    const int w    = threadIdx.x;         // 0..447

    int lo = h0 - 3;
    lo = lo < 0 ? 0 : (lo > HN - BAND ? HN - BAND : lo);

    const float* imgb = img + (size_t)b * CN * HW;
    const float* flob = flo + (size_t)b * 2 * HW;

    // ---- per-pixel setup, channel-invariant ----
    float wa[R], wb[R], wc[R], wd[R];
    int sA[R], sB[R];       // band-relative LDS word offsets
    int gA[R], gB[R];       // plane-relative global word offsets (fallback)
    int dx_[R];
    bool fb[R];
    bool anyfb = false;
#pragma unroll
    for (int r = 0; r < R; ++r) {
        const int h = h0 + r;
        const int hw = h * WN + w;
        const float fx = flob[hw];
        const float fy = flob[HW + hw];
        const float x = (float)w + fx;
        const float y = (float)h + fy;
        int x0 = (int)x;                 // trunc toward zero (matches ref)
        int x1 = x0 + 1;
        int y0 = (int)y;
        int y1 = y0 + 1;
        x0 = min(max(x0, 0), WN - 1);
        x1 = min(max(x1, 0), WN - 1);
        y0 = min(max(y0, 0), HN - 1);
        y1 = min(max(y1, 0), HN - 1);
        const float x0f = (float)x0, x1f = (float)x1;
        const float y0f = (float)y0, y1f = (float)y1;
        wa[r] = (x1f - x) * (y1f - y);
        wb[r] = (x1f - x) * (y - y0f);
        wc[r] = (x - x0f) * (y1f - y);
        wd[r] = (x - x0f) * (y - y0f);
        dx_[r] = x1 - x0;                // 0 only at l/r edge clip
        const bool inband = (y0 >= lo) && (y1 <= lo + BAND - 1);
        fb[r] = !inband;
        anyfb |= fb[r];
        const int rA = min(max(y0 - lo, 0), BAND - 1);
        const int rB = min(max(y1 - lo, 0), BAND - 1);
        sA[r] = rA * WN + x0;
        sB[r] = rB * WN + x0;
        gA[r] = y0 * WN + x0;
        gB[r] = y1 * WN + x0;
    }
    const bool dirty = __any(anyfb);    // wave-uniform, rare

    const int wave = threadIdx.x >> 6;   // 0..6
    const int lane = threadIdx.x & 63;

    // ---- staging: 10 rows x 448 = 4480 words = 17x1KB chunks + 2x256B tails ----
    auto stage = [&](int bufi, int c) {          // c = global channel
        const float* src = imgb + (size_t)c * HW + (size_t)lo * WN;
        float* dst = &lds[bufi][0];
        for (int s = wave; s < 17; s += 7) {
            __builtin_amdgcn_global_load_lds(
                (glb_v*)(src + s * 256 + lane * 4),
                (lds_v*)(dst + s * 256), 16, 0, 0);
        }
        if (wave < 2) {
            const int base = 17 * 256 + wave * 64;
            __builtin_amdgcn_global_load_lds(
                (glb_v*)(src + base + lane),
                (lds_v*)(dst + base), 4, 0, 0);
        }
    };

    stage(0, ch0 + 0);
    stage(1, ch0 + 1);
    __syncthreads();

    float* outp = out + (size_t)b * CN * HW + (size_t)ch0 * HW + (size_t)h0 * WN + w;

    for (int k = 0; k < ROUNDS; ++k) {
        const int m = 2 * k;                       // local channel of this round
        if (k + 1 < ROUNDS) {
            stage((m + 2) & 3, ch0 + m + 2);
            stage((m + 3) & 3, ch0 + m + 3);
        }

        const float* bufA = &lds[m & 3][0];
        const float* bufB = &lds[(m + 1) & 3][0];
        float oA[R], oB[R];
        if (!dirty) {
#pragma unroll
            for (int r = 0; r < R; ++r) {
                const float Aa0 = bufA[sA[r]];
                const float Aa1 = bufA[sA[r] + 1];   // ds_read2_b32 pair
                const float Ab0 = bufA[sB[r]];
                const float Ab1 = bufA[sB[r] + 1];
                const float Ba0 = bufB[sA[r]];
                const float Ba1 = bufB[sA[r] + 1];
                const float Bb0 = bufB[sB[r]];
                const float Bb1 = bufB[sB[r] + 1];
                const float AIc = dx_[r] ? Aa1 : Aa0;
                const float AId = dx_[r] ? Ab1 : Ab0;
                const float BIc = dx_[r] ? Ba1 : Ba0;
                const float BId = dx_[r] ? Bb1 : Bb0;
                oA[r] = wa[r] * Aa0 + wb[r] * Ab0 + wc[r] * AIc + wd[r] * AId;
                oB[r] = wa[r] * Ba0 + wb[r] * Bb0 + wc[r] * BIc + wd[r] * BId;
            }
        } else {
            const float* pgA = imgb + (size_t)(ch0 + m) * HW;
            const float* pgB = imgb + (size_t)(ch0 + m + 1) * HW;
#pragma unroll
            for (int r = 0; r < R; ++r) {
                float Aa0 = bufA[sA[r]];
                float Aa1 = bufA[sA[r] + 1];
                float Ab0 = bufA[sB[r]];
                float Ab1 = bufA[sB[r] + 1];
                float Ba0 = bufB[sA[r]];
                float Ba1 = bufB[sA[r] + 1];
                float Bb0 = bufB[sB[r]];
                float Bb1 = bufB[sB[r] + 1];
                if (fb[r]) {
                    Aa0 = pgA[gA[r]];
                    Aa1 = pgA[gA[r] + dx_[r]];
                    Ab0 = pgA[gB[r]];
                    Ab1 = pgA[gB[r] + dx_[r]];
                    Ba0 = pgB[gA[r]];
                    Ba1 = pgB[gA[r] + dx_[r]];
                    Bb0 = pgB[gB[r]];
                    Bb1 = pgB[gB[r] + dx_[r]];
                }
                const float AIc = dx_[r] ? Aa1 : Aa0;
                const float AId = dx_[r] ? Ab1 : Ab0;
                const float BIc = dx_[r] ? Ba1 : Ba0;
                const float BId = dx_[r] ? Bb1 : Bb0;
                oA[r] = wa[r] * Aa0 + wb[r] * Ab0 + wc[r] * AIc + wd[r] * AId;
                oB[r] = wa[r] * Ba0 + wb[r] * Bb0 + wc[r] * BIc + wd[r] * BId;
            }
        }
#pragma unroll
        for (int r = 0; r < R; ++r) {
            outp[(size_t)m * HW + r * WN] = oA[r];
            outp[(size_t)(m + 1) * HW + r * WN] = oB[r];
        }
        __syncthreads();   // drain (stage k+1 landed) + barrier, once per 2 channels
    }
}

extern "C" void kernel_launch(void* const* d_in, const int* in_sizes, int n_in,
                              void* d_out, int out_size, void* d_ws, size_t ws_size,
                              hipStream_t stream) {
    const float* img = (const float*)d_in[0];
    const float* flo = (const float*)d_in[1];
    float* out = (float*)d_out;

    const int grid = BN * (HN / R) * CSPLIT;   // 1024 blocks
    warp_kernel<<<grid, TPB, 0, stream>>>(img, flo, out);
}